// Round 1
// baseline (324.886 us; speedup 1.0000x reference)
//
#include <hip/hip_runtime.h>
#include <math.h>

#define BDIM 8
#define IMG 224
#define PP 16
#define GG 14
#define NN 196
#define PD 256
#define DD 128
#define DFFV 256
#define CC 1000

#define NEGINF (-INFINITY)

struct TransArgs {
  const float* src[12];
  float* dst[12];
  int R[12];
  int C[12];
};

// dst (C,R) <- src (R,C):  dst[c*R + r] = src[r*C + c]
__global__ void transpose_all(TransArgs a) {
  int m = blockIdx.y;
  int R = a.R[m], C = a.C[m];
  const float* s = a.src[m];
  float* d = a.dst[m];
  int total = R * C;
  for (int idx = blockIdx.x * blockDim.x + threadIdx.x; idx < total;
       idx += gridDim.x * blockDim.x) {
    int r = idx / C, c = idx - r * C;
    d[c * R + r] = s[idx];
  }
}

// block per (b, gi): 256 threads; halves handle 7 gj each.
// h[b,n,d] = max_j(patch[n][j] + embed_W[d][j]) + pos[n][d]
__global__ void embed_kernel(const float* __restrict__ x, const float* __restrict__ eWT,
                             const float* __restrict__ pos, float* __restrict__ h) {
  int b = blockIdx.x / GG, gi = blockIdx.x % GG;
  __shared__ float patch[GG][PD];  // 14 KB
  for (int e = threadIdx.x; e < GG * PD; e += 256) {
    int gj = e >> 8, j = e & 255, pi = j >> 4, pj = j & 15;
    patch[gj][j] = x[(b * IMG + gi * PP + pi) * IMG + gj * PP + pj];
  }
  __syncthreads();
  int d = threadIdx.x & 127, half = threadIdx.x >> 7;
  float acc[7];
#pragma unroll
  for (int t = 0; t < 7; t++) acc[t] = NEGINF;
  for (int j = 0; j < PD; j++) {
    float w = eWT[j * DD + d];
#pragma unroll
    for (int t = 0; t < 7; t++) acc[t] = fmaxf(acc[t], patch[half * 7 + t][j] + w);
  }
#pragma unroll
  for (int t = 0; t < 7; t++) {
    int n = gi * GG + half * 7 + t;
    h[(b * NN + n) * DD + d] = acc[t] + pos[n * DD + d];
  }
}

// grid (49, B), 384 threads: thread groups of 128 compute q / k / v.
// xn = h - rowmax(h); q[i] = max_j(xn[j] + W[i][j]); k stored transposed.
__global__ void qkv_kernel(const float* __restrict__ h, const float* __restrict__ qWT,
                           const float* __restrict__ kWT, const float* __restrict__ vWT,
                           float* __restrict__ q, float* __restrict__ kT,
                           float* __restrict__ v) {
  int nt = blockIdx.x, b = blockIdx.y;
  int n0 = nt * 4;
  __shared__ float xn[4][DD];
  __shared__ float mxs[4];
  int t = threadIdx.x;
  for (int e = t; e < 4 * DD; e += 384)
    xn[e >> 7][e & 127] = h[(b * NN + n0 + (e >> 7)) * DD + (e & 127)];
  __syncthreads();
  if (t < 128) {
    int r = t >> 5, l = t & 31;
    float m = fmaxf(fmaxf(xn[r][l], xn[r][l + 32]), fmaxf(xn[r][l + 64], xn[r][l + 96]));
#pragma unroll
    for (int mask = 16; mask >= 1; mask >>= 1) m = fmaxf(m, __shfl_xor(m, mask));
    if (l == 0) mxs[r] = m;
  }
  __syncthreads();
  for (int e = t; e < 4 * DD; e += 384) xn[e >> 7][e & 127] -= mxs[e >> 7];
  __syncthreads();
  int m = t >> 7, d = t & 127;
  const float* W = (m == 0) ? qWT : (m == 1 ? kWT : vWT);
  float acc[4];
#pragma unroll
  for (int r = 0; r < 4; r++) acc[r] = NEGINF;
  for (int j = 0; j < DD; j++) {
    float w = W[j * DD + d];
#pragma unroll
    for (int r = 0; r < 4; r++) acc[r] = fmaxf(acc[r], xn[r][j] + w);
  }
  if (m == 0) {
#pragma unroll
    for (int r = 0; r < 4; r++) q[(b * NN + n0 + r) * DD + d] = acc[r];
  } else if (m == 1) {
#pragma unroll
    for (int r = 0; r < 4; r++) kT[(b * DD + d) * NN + n0 + r] = acc[r];
  } else {
#pragma unroll
    for (int r = 0; r < 4; r++) v[(b * NN + n0 + r) * DD + d] = acc[r];
  }
}

// grid (49, B), 256 threads; 4 query rows per block.
// scores (no row-max needed: canceled by pnorm), out, pnorm, residual max into h.
__global__ void attn_kernel(const float* __restrict__ q, const float* __restrict__ kT,
                            const float* __restrict__ v, float* __restrict__ h) {
  int it = blockIdx.x, b = blockIdx.y;
  int i0 = it * 4;
  __shared__ float qs[4][DD];
  __shared__ float sc[4][NN];
  __shared__ float red[2][4];
  int t = threadIdx.x;
  for (int e = t; e < 4 * DD; e += 256)
    qs[e >> 7][e & 127] = q[(b * NN + i0 + (e >> 7)) * DD + (e & 127)];
  __syncthreads();
  if (t < NN) {
    float s0 = NEGINF, s1 = NEGINF, s2 = NEGINF, s3 = NEGINF;
    for (int d = 0; d < DD; d++) {
      float kv = kT[(b * DD + d) * NN + t];
      s0 = fmaxf(s0, qs[0][d] + kv);
      s1 = fmaxf(s1, qs[1][d] + kv);
      s2 = fmaxf(s2, qs[2][d] + kv);
      s3 = fmaxf(s3, qs[3][d] + kv);
    }
    sc[0][t] = s0; sc[1][t] = s1; sc[2][t] = s2; sc[3][t] = s3;
  }
  __syncthreads();
  float o[4];
#pragma unroll
  for (int r = 0; r < 4; r++) o[r] = NEGINF;
  if (t < DD) {
    for (int j = 0; j < NN; j++) {
      float vv = v[(b * NN + j) * DD + t];
#pragma unroll
      for (int r = 0; r < 4; r++) o[r] = fmaxf(o[r], sc[r][j] + vv);
    }
  }
  int lane = t & 63, wv = t >> 6;
#pragma unroll
  for (int r = 0; r < 4; r++) {
    float mval = o[r];
#pragma unroll
    for (int mask = 32; mask >= 1; mask >>= 1) mval = fmaxf(mval, __shfl_xor(mval, mask));
    if (lane == 0 && wv < 2) red[wv][r] = mval;
  }
  __syncthreads();
  if (t < DD) {
#pragma unroll
    for (int r = 0; r < 4; r++) {
      float omax = fmaxf(red[0][r], red[1][r]);
      int idx = (b * NN + i0 + r) * DD + t;
      h[idx] = fmaxf(h[idx], o[r] - omax);
    }
  }
}

// grid (49, B), 256 threads. h1 = max(trop_mm(pnorm(h), f1W), tau)
__global__ void ffn1_kernel(const float* __restrict__ h, const float* __restrict__ f1WT,
                            const float* __restrict__ tau, float* __restrict__ h1) {
  int nt = blockIdx.x, b = blockIdx.y, n0 = nt * 4;
  __shared__ float xn[4][DD];
  __shared__ float mxs[4];
  int t = threadIdx.x;
  for (int e = t; e < 4 * DD; e += 256)
    xn[e >> 7][e & 127] = h[(b * NN + n0 + (e >> 7)) * DD + (e & 127)];
  __syncthreads();
  if (t < 128) {
    int r = t >> 5, l = t & 31;
    float m = fmaxf(fmaxf(xn[r][l], xn[r][l + 32]), fmaxf(xn[r][l + 64], xn[r][l + 96]));
#pragma unroll
    for (int mask = 16; mask >= 1; mask >>= 1) m = fmaxf(m, __shfl_xor(m, mask));
    if (l == 0) mxs[r] = m;
  }
  __syncthreads();
  for (int e = t; e < 4 * DD; e += 256) xn[e >> 7][e & 127] -= mxs[e >> 7];
  __syncthreads();
  float tv = tau[0];
  float acc[4];
#pragma unroll
  for (int r = 0; r < 4; r++) acc[r] = NEGINF;
  for (int j = 0; j < DD; j++) {
    float w = f1WT[j * DFFV + t];
#pragma unroll
    for (int r = 0; r < 4; r++) acc[r] = fmaxf(acc[r], xn[r][j] + w);
  }
#pragma unroll
  for (int r = 0; r < 4; r++)
    h1[(b * NN + n0 + r) * DFFV + t] = fmaxf(acc[r], tv);
}

// grid (49, B), 128 threads. ff = pnorm(trop_mm(h1, f2W)); h = max(h, ff)
__global__ void ffn2_kernel(const float* __restrict__ h1, const float* __restrict__ f2WT,
                            float* __restrict__ h) {
  int nt = blockIdx.x, b = blockIdx.y, n0 = nt * 4;
  __shared__ float hs[4][DFFV];
  __shared__ float red[2][4];
  int t = threadIdx.x;
  for (int e = t; e < 4 * DFFV; e += 128)
    hs[e >> 8][e & 255] = h1[(b * NN + n0 + (e >> 8)) * DFFV + (e & 255)];
  __syncthreads();
  float acc[4];
#pragma unroll
  for (int r = 0; r < 4; r++) acc[r] = NEGINF;
  for (int j = 0; j < DFFV; j++) {
    float w = f2WT[j * DD + t];
#pragma unroll
    for (int r = 0; r < 4; r++) acc[r] = fmaxf(acc[r], hs[r][j] + w);
  }
  int lane = t & 63, wv = t >> 6;
#pragma unroll
  for (int r = 0; r < 4; r++) {
    float mval = acc[r];
#pragma unroll
    for (int mask = 32; mask >= 1; mask >>= 1) mval = fmaxf(mval, __shfl_xor(mval, mask));
    if (lane == 0) red[wv][r] = mval;
  }
  __syncthreads();
#pragma unroll
  for (int r = 0; r < 4; r++) {
    float omax = fmaxf(red[0][r], red[1][r]);
    int idx = (b * NN + n0 + r) * DD + t;
    h[idx] = fmaxf(h[idx], acc[r] - omax);
  }
}

// grid (8, B), 128 threads. pooled = max_n h; out = trop_mm(pooled, head_W)*scale
__global__ void head_kernel(const float* __restrict__ h, const float* __restrict__ hWT,
                            const float* __restrict__ lscale, float* __restrict__ out) {
  int ct = blockIdx.x, b = blockIdx.y;
  __shared__ float pooled[DD];
  int t = threadIdx.x;
  float pm = NEGINF;
  for (int n = 0; n < NN; n++) pm = fmaxf(pm, h[(b * NN + n) * DD + t]);
  pooled[t] = pm;
  __syncthreads();
  int c = ct * 128 + t;
  if (c < CC) {
    float acc = NEGINF;
    for (int d = 0; d < DD; d++) acc = fmaxf(acc, pooled[d] + hWT[d * CC + c]);
    out[b * CC + c] = acc * lscale[0];
  }
}

extern "C" void kernel_launch(void* const* d_in, const int* in_sizes, int n_in,
                              void* d_out, int out_size, void* d_ws, size_t ws_size,
                              hipStream_t stream) {
  const float* x = (const float*)d_in[0];
  const float* embed_W = (const float*)d_in[1];
  const float* pos = (const float*)d_in[2];
  const float* qW[2] = {(const float*)d_in[3], (const float*)d_in[9]};
  const float* kW[2] = {(const float*)d_in[4], (const float*)d_in[10]};
  const float* vW[2] = {(const float*)d_in[5], (const float*)d_in[11]};
  const float* f1W[2] = {(const float*)d_in[6], (const float*)d_in[12]};
  const float* f2W[2] = {(const float*)d_in[7], (const float*)d_in[13]};
  const float* tau[2] = {(const float*)d_in[8], (const float*)d_in[14]};
  const float* headW = (const float*)d_in[15];
  const float* lscale = (const float*)d_in[16];
  float* out = (float*)d_out;

  float* ws = (float*)d_ws;
  size_t o = 0;
  float* eWT = ws + o; o += (size_t)PD * DD;
  float* qWT[2]; float* kWT[2]; float* vWT[2]; float* f1WT[2]; float* f2WT[2];
  for (int l = 0; l < 2; l++) {
    qWT[l] = ws + o; o += (size_t)DD * DD;
    kWT[l] = ws + o; o += (size_t)DD * DD;
    vWT[l] = ws + o; o += (size_t)DD * DD;
  }
  for (int l = 0; l < 2; l++) { f1WT[l] = ws + o; o += (size_t)DD * DFFV; }
  for (int l = 0; l < 2; l++) { f2WT[l] = ws + o; o += (size_t)DFFV * DD; }
  float* hWT = ws + o; o += (size_t)DD * CC;
  float* h = ws + o; o += (size_t)BDIM * NN * DD;
  float* qb = ws + o; o += (size_t)BDIM * NN * DD;
  float* kTb = ws + o; o += (size_t)BDIM * NN * DD;
  float* vb = ws + o; o += (size_t)BDIM * NN * DD;
  float* h1 = ws + o; o += (size_t)BDIM * NN * DFFV;

  TransArgs ta;
  // embed_W (D, PD)
  ta.src[0] = embed_W; ta.dst[0] = eWT; ta.R[0] = DD; ta.C[0] = PD;
  // q/k/v per layer (D, D)
  for (int l = 0; l < 2; l++) {
    ta.src[1 + l * 3] = qW[l]; ta.dst[1 + l * 3] = qWT[l]; ta.R[1 + l * 3] = DD; ta.C[1 + l * 3] = DD;
    ta.src[2 + l * 3] = kW[l]; ta.dst[2 + l * 3] = kWT[l]; ta.R[2 + l * 3] = DD; ta.C[2 + l * 3] = DD;
    ta.src[3 + l * 3] = vW[l]; ta.dst[3 + l * 3] = vWT[l]; ta.R[3 + l * 3] = DD; ta.C[3 + l * 3] = DD;
  }
  // f1 (DFF, D)
  ta.src[7] = f1W[0]; ta.dst[7] = f1WT[0]; ta.R[7] = DFFV; ta.C[7] = DD;
  ta.src[8] = f1W[1]; ta.dst[8] = f1WT[1]; ta.R[8] = DFFV; ta.C[8] = DD;
  // f2 (D, DFF)
  ta.src[9] = f2W[0]; ta.dst[9] = f2WT[0]; ta.R[9] = DD; ta.C[9] = DFFV;
  ta.src[10] = f2W[1]; ta.dst[10] = f2WT[1]; ta.R[10] = DD; ta.C[10] = DFFV;
  // head (C, D)
  ta.src[11] = headW; ta.dst[11] = hWT; ta.R[11] = CC; ta.C[11] = DD;

  transpose_all<<<dim3(64, 12), 256, 0, stream>>>(ta);
  embed_kernel<<<BDIM * GG, 256, 0, stream>>>(x, eWT, pos, h);
  for (int l = 0; l < 2; l++) {
    qkv_kernel<<<dim3(49, BDIM), 384, 0, stream>>>(h, qWT[l], kWT[l], vWT[l], qb, kTb, vb);
    attn_kernel<<<dim3(49, BDIM), 256, 0, stream>>>(qb, kTb, vb, h);
    ffn1_kernel<<<dim3(49, BDIM), 256, 0, stream>>>(h, f1WT[l], tau[l], h1);
    ffn2_kernel<<<dim3(49, BDIM), 128, 0, stream>>>(h1, f2WT[l], h);
  }
  head_kernel<<<dim3(8, BDIM), 128, 0, stream>>>(h, hWT, lscale, out);
}

// Round 2
// 278.737 us; speedup vs baseline: 1.1656x; 1.1656x over previous
//
#include <hip/hip_runtime.h>
#include <math.h>

#define BDIM 8
#define IMG 224
#define PP 16
#define GG 14
#define NN 196
#define PD 256
#define DD 128
#define DFFV 256
#define CC 1000

#define NEGINF (-INFINITY)

struct TransArgs {
  const float* src[12];
  float* dst[12];
  int R[12];
  int C[12];
};

// dst (C,R) <- src (R,C):  dst[c*R + r] = src[r*C + c]
__global__ void transpose_all(TransArgs a) {
  int m = blockIdx.y;
  int R = a.R[m], C = a.C[m];
  const float* s = a.src[m];
  float* d = a.dst[m];
  int total = R * C;
  for (int idx = blockIdx.x * blockDim.x + threadIdx.x; idx < total;
       idx += gridDim.x * blockDim.x) {
    int r = idx / C, c = idx - r * C;
    d[c * R + r] = s[idx];
  }
}

// block per (b, gi): 256 threads; halves handle 7 gj each.
// h[b,n,d] = max_j(patch[n][j] + embed_W[d][j]) + pos[n][d]
__global__ void embed_kernel(const float* __restrict__ x, const float* __restrict__ eWT,
                             const float* __restrict__ pos, float* __restrict__ h) {
  int b = blockIdx.x / GG, gi = blockIdx.x % GG;
  __shared__ float patch[GG][PD];  // 14 KB
  for (int e = threadIdx.x; e < GG * PD; e += 256) {
    int gj = e >> 8, j = e & 255, pi = j >> 4, pj = j & 15;
    patch[gj][j] = x[(b * IMG + gi * PP + pi) * IMG + gj * PP + pj];
  }
  __syncthreads();
  int d = threadIdx.x & 127, half = threadIdx.x >> 7;
  float acc[7];
#pragma unroll
  for (int t = 0; t < 7; t++) acc[t] = NEGINF;
#pragma unroll 8
  for (int j = 0; j < PD; j++) {
    float w = eWT[j * DD + d];
#pragma unroll
    for (int t = 0; t < 7; t++) acc[t] = fmaxf(acc[t], patch[half * 7 + t][j] + w);
  }
#pragma unroll
  for (int t = 0; t < 7; t++) {
    int n = gi * GG + half * 7 + t;
    h[(b * NN + n) * DD + d] = acc[t] + pos[n * DD + d];
  }
}

// grid (49, B), 384 threads: thread groups of 128 compute q / k / v.
// pnorm commutes with trop_mm: compute on raw x, subtract rowmax at output.
__global__ void qkv_kernel(const float* __restrict__ h, const float* __restrict__ qWT,
                           const float* __restrict__ kWT, const float* __restrict__ vWT,
                           float* __restrict__ q, float* __restrict__ kT,
                           float* __restrict__ v) {
  int nt = blockIdx.x, b = blockIdx.y;
  int n0 = nt * 4;
  __shared__ float xs[4][DD];
  __shared__ float mxs[4];
  int t = threadIdx.x;
  for (int e = t; e < 4 * DD; e += 384)
    xs[e >> 7][e & 127] = h[(b * NN + n0 + (e >> 7)) * DD + (e & 127)];
  __syncthreads();
  if (t < 128) {
    int r = t >> 5, l = t & 31;
    float m = fmaxf(fmaxf(xs[r][l], xs[r][l + 32]), fmaxf(xs[r][l + 64], xs[r][l + 96]));
#pragma unroll
    for (int mask = 16; mask >= 1; mask >>= 1) m = fmaxf(m, __shfl_xor(m, mask));
    if (l == 0) mxs[r] = m;
  }
  __syncthreads();
  int m = t >> 7, d = t & 127;
  const float* W = (m == 0) ? qWT : (m == 1 ? kWT : vWT);
  float acc[4];
#pragma unroll
  for (int r = 0; r < 4; r++) acc[r] = NEGINF;
#pragma unroll 8
  for (int j = 0; j < DD; j++) {
    float w = W[j * DD + d];
#pragma unroll
    for (int r = 0; r < 4; r++) acc[r] = fmaxf(acc[r], xs[r][j] + w);
  }
  if (m == 0) {
#pragma unroll
    for (int r = 0; r < 4; r++) q[(b * NN + n0 + r) * DD + d] = acc[r] - mxs[r];
  } else if (m == 1) {
#pragma unroll
    for (int r = 0; r < 4; r++) kT[(b * DD + d) * NN + n0 + r] = acc[r] - mxs[r];
  } else {
#pragma unroll
    for (int r = 0; r < 4; r++) v[(b * NN + n0 + r) * DD + d] = acc[r] - mxs[r];
  }
}

// grid (49, B), 256 threads; 4 query rows per block.
// scores (no row-max needed: canceled by pnorm), out, pnorm, residual max into h.
__global__ void attn_kernel(const float* __restrict__ q, const float* __restrict__ kT,
                            const float* __restrict__ v, float* __restrict__ h) {
  int it = blockIdx.x, b = blockIdx.y;
  int i0 = it * 4;
  __shared__ float qs[4][DD];
  __shared__ float sc[4][NN];
  __shared__ float red[2][4];
  int t = threadIdx.x;
  for (int e = t; e < 4 * DD; e += 256)
    qs[e >> 7][e & 127] = q[(b * NN + i0 + (e >> 7)) * DD + (e & 127)];
  __syncthreads();
  if (t < NN) {
    float s0 = NEGINF, s1 = NEGINF, s2 = NEGINF, s3 = NEGINF;
#pragma unroll 8
    for (int d = 0; d < DD; d++) {
      float kv = kT[(b * DD + d) * NN + t];
      s0 = fmaxf(s0, qs[0][d] + kv);
      s1 = fmaxf(s1, qs[1][d] + kv);
      s2 = fmaxf(s2, qs[2][d] + kv);
      s3 = fmaxf(s3, qs[3][d] + kv);
    }
    sc[0][t] = s0; sc[1][t] = s1; sc[2][t] = s2; sc[3][t] = s3;
  }
  __syncthreads();
  float o[4];
#pragma unroll
  for (int r = 0; r < 4; r++) o[r] = NEGINF;
  if (t < DD) {
#pragma unroll 4
    for (int j = 0; j < NN; j++) {
      float vv = v[(b * NN + j) * DD + t];
#pragma unroll
      for (int r = 0; r < 4; r++) o[r] = fmaxf(o[r], sc[r][j] + vv);
    }
  }
  int lane = t & 63, wv = t >> 6;
#pragma unroll
  for (int r = 0; r < 4; r++) {
    float mval = o[r];
#pragma unroll
    for (int mask = 32; mask >= 1; mask >>= 1) mval = fmaxf(mval, __shfl_xor(mval, mask));
    if (lane == 0 && wv < 2) red[wv][r] = mval;
  }
  __syncthreads();
  if (t < DD) {
#pragma unroll
    for (int r = 0; r < 4; r++) {
      float omax = fmaxf(red[0][r], red[1][r]);
      int idx = (b * NN + i0 + r) * DD + t;
      h[idx] = fmaxf(h[idx], o[r] - omax);
    }
  }
}

// grid (49, B), 256 threads. h1 = max(trop_mm(pnorm(h), f1W), tau)
// pnorm folded to output: max(y - m, tau)
__global__ void ffn1_kernel(const float* __restrict__ h, const float* __restrict__ f1WT,
                            const float* __restrict__ tau, float* __restrict__ h1) {
  int nt = blockIdx.x, b = blockIdx.y, n0 = nt * 4;
  __shared__ float xs[4][DD];
  __shared__ float mxs[4];
  int t = threadIdx.x;
  for (int e = t; e < 4 * DD; e += 256)
    xs[e >> 7][e & 127] = h[(b * NN + n0 + (e >> 7)) * DD + (e & 127)];
  __syncthreads();
  if (t < 128) {
    int r = t >> 5, l = t & 31;
    float m = fmaxf(fmaxf(xs[r][l], xs[r][l + 32]), fmaxf(xs[r][l + 64], xs[r][l + 96]));
#pragma unroll
    for (int mask = 16; mask >= 1; mask >>= 1) m = fmaxf(m, __shfl_xor(m, mask));
    if (l == 0) mxs[r] = m;
  }
  __syncthreads();
  float tv = tau[0];
  float acc[4];
#pragma unroll
  for (int r = 0; r < 4; r++) acc[r] = NEGINF;
#pragma unroll 8
  for (int j = 0; j < DD; j++) {
    float w = f1WT[j * DFFV + t];
#pragma unroll
    for (int r = 0; r < 4; r++) acc[r] = fmaxf(acc[r], xs[r][j] + w);
  }
#pragma unroll
  for (int r = 0; r < 4; r++)
    h1[(b * NN + n0 + r) * DFFV + t] = fmaxf(acc[r] - mxs[r], tv);
}

// grid (49, B), 128 threads. ff = pnorm(trop_mm(h1, f2W)); h = max(h, ff)
__global__ void ffn2_kernel(const float* __restrict__ h1, const float* __restrict__ f2WT,
                            float* __restrict__ h) {
  int nt = blockIdx.x, b = blockIdx.y, n0 = nt * 4;
  __shared__ float hs[4][DFFV];
  __shared__ float red[2][4];
  int t = threadIdx.x;
  for (int e = t; e < 4 * DFFV; e += 128)
    hs[e >> 8][e & 255] = h1[(b * NN + n0 + (e >> 8)) * DFFV + (e & 255)];
  __syncthreads();
  float acc[4];
#pragma unroll
  for (int r = 0; r < 4; r++) acc[r] = NEGINF;
#pragma unroll 8
  for (int j = 0; j < DFFV; j++) {
    float w = f2WT[j * DD + t];
#pragma unroll
    for (int r = 0; r < 4; r++) acc[r] = fmaxf(acc[r], hs[r][j] + w);
  }
  int lane = t & 63, wv = t >> 6;
#pragma unroll
  for (int r = 0; r < 4; r++) {
    float mval = acc[r];
#pragma unroll
    for (int mask = 32; mask >= 1; mask >>= 1) mval = fmaxf(mval, __shfl_xor(mval, mask));
    if (lane == 0) red[wv][r] = mval;
  }
  __syncthreads();
#pragma unroll
  for (int r = 0; r < 4; r++) {
    float omax = fmaxf(red[0][r], red[1][r]);
    int idx = (b * NN + n0 + r) * DD + t;
    h[idx] = fmaxf(h[idx], acc[r] - omax);
  }
}

// grid (8, B), 128 threads. pooled = max_n h; out = trop_mm(pooled, head_W)*scale
__global__ void head_kernel(const float* __restrict__ h, const float* __restrict__ hWT,
                            const float* __restrict__ lscale, float* __restrict__ out) {
  int ct = blockIdx.x, b = blockIdx.y;
  __shared__ float pooled[DD];
  int t = threadIdx.x;
  float pm = NEGINF;
#pragma unroll 8
  for (int n = 0; n < NN; n++) pm = fmaxf(pm, h[(b * NN + n) * DD + t]);
  pooled[t] = pm;
  __syncthreads();
  int c = ct * 128 + t;
  float acc = NEGINF;
#pragma unroll 8
  for (int d = 0; d < DD; d++) acc = fmaxf(acc, pooled[d] + hWT[d * CC + c]);
  if (c < CC) out[b * CC + c] = acc * lscale[0];
}

extern "C" void kernel_launch(void* const* d_in, const int* in_sizes, int n_in,
                              void* d_out, int out_size, void* d_ws, size_t ws_size,
                              hipStream_t stream) {
  const float* x = (const float*)d_in[0];
  const float* embed_W = (const float*)d_in[1];
  const float* pos = (const float*)d_in[2];
  const float* qW[2] = {(const float*)d_in[3], (const float*)d_in[9]};
  const float* kW[2] = {(const float*)d_in[4], (const float*)d_in[10]};
  const float* vW[2] = {(const float*)d_in[5], (const float*)d_in[11]};
  const float* f1W[2] = {(const float*)d_in[6], (const float*)d_in[12]};
  const float* f2W[2] = {(const float*)d_in[7], (const float*)d_in[13]};
  const float* tau[2] = {(const float*)d_in[8], (const float*)d_in[14]};
  const float* headW = (const float*)d_in[15];
  const float* lscale = (const float*)d_in[16];
  float* out = (float*)d_out;

  float* ws = (float*)d_ws;
  size_t o = 0;
  float* eWT = ws + o; o += (size_t)PD * DD;
  float* qWT[2]; float* kWT[2]; float* vWT[2]; float* f1WT[2]; float* f2WT[2];
  for (int l = 0; l < 2; l++) {
    qWT[l] = ws + o; o += (size_t)DD * DD;
    kWT[l] = ws + o; o += (size_t)DD * DD;
    vWT[l] = ws + o; o += (size_t)DD * DD;
  }
  for (int l = 0; l < 2; l++) { f1WT[l] = ws + o; o += (size_t)DD * DFFV; }
  for (int l = 0; l < 2; l++) { f2WT[l] = ws + o; o += (size_t)DFFV * DD; }
  float* hWT = ws + o; o += (size_t)DD * CC;
  float* h = ws + o; o += (size_t)BDIM * NN * DD;
  float* qb = ws + o; o += (size_t)BDIM * NN * DD;
  float* kTb = ws + o; o += (size_t)BDIM * NN * DD;
  float* vb = ws + o; o += (size_t)BDIM * NN * DD;
  float* h1 = ws + o; o += (size_t)BDIM * NN * DFFV;

  TransArgs ta;
  ta.src[0] = embed_W; ta.dst[0] = eWT; ta.R[0] = DD; ta.C[0] = PD;
  for (int l = 0; l < 2; l++) {
    ta.src[1 + l * 3] = qW[l]; ta.dst[1 + l * 3] = qWT[l]; ta.R[1 + l * 3] = DD; ta.C[1 + l * 3] = DD;
    ta.src[2 + l * 3] = kW[l]; ta.dst[2 + l * 3] = kWT[l]; ta.R[2 + l * 3] = DD; ta.C[2 + l * 3] = DD;
    ta.src[3 + l * 3] = vW[l]; ta.dst[3 + l * 3] = vWT[l]; ta.R[3 + l * 3] = DD; ta.C[3 + l * 3] = DD;
  }
  ta.src[7] = f1W[0]; ta.dst[7] = f1WT[0]; ta.R[7] = DFFV; ta.C[7] = DD;
  ta.src[8] = f1W[1]; ta.dst[8] = f1WT[1]; ta.R[8] = DFFV; ta.C[8] = DD;
  ta.src[9] = f2W[0]; ta.dst[9] = f2WT[0]; ta.R[9] = DD; ta.C[9] = DFFV;
  ta.src[10] = f2W[1]; ta.dst[10] = f2WT[1]; ta.R[10] = DD; ta.C[10] = DFFV;
  ta.src[11] = headW; ta.dst[11] = hWT; ta.R[11] = CC; ta.C[11] = DD;

  transpose_all<<<dim3(64, 12), 256, 0, stream>>>(ta);
  embed_kernel<<<BDIM * GG, 256, 0, stream>>>(x, eWT, pos, h);
  for (int l = 0; l < 2; l++) {
    qkv_kernel<<<dim3(49, BDIM), 384, 0, stream>>>(h, qWT[l], kWT[l], vWT[l], qb, kTb, vb);
    attn_kernel<<<dim3(49, BDIM), 256, 0, stream>>>(qb, kTb, vb, h);
    ffn1_kernel<<<dim3(49, BDIM), 256, 0, stream>>>(h, f1WT[l], tau[l], h1);
    ffn2_kernel<<<dim3(49, BDIM), 128, 0, stream>>>(h1, f2WT[l], h);
  }
  head_kernel<<<dim3(8, BDIM), 128, 0, stream>>>(h, hWT, lscale, out);
}

// Round 3
// 223.221 us; speedup vs baseline: 1.4554x; 1.2487x over previous
//
#include <hip/hip_runtime.h>
#include <math.h>

#define BDIM 8
#define IMG 224
#define PP 16
#define GG 14
#define NN 196
#define PD 256
#define DD 128
#define DFFV 256
#define CC 1000

#define NEGINF (-INFINITY)

// ---------------- embed: block per (b, gi), 256 threads ----------------
// h[b, gi*14+gj, d] = max_j(patch[gj][j] + embed_W[d][j]) + pos[n][d]
// embed_W kept in ORIGINAL (D, PD) layout: per-thread float4 rows.
__global__ void embed_kernel(const float* __restrict__ x, const float* __restrict__ eW,
                             const float* __restrict__ pos, float* __restrict__ h) {
  int b = blockIdx.x / GG, gi = blockIdx.x % GG;
  __shared__ float patch[GG][PD];  // 14 KB
  int t = threadIdx.x;
  // stage patches as float4: 896 float4s
  for (int e = t; e < GG * 64; e += 256) {
    int gj = e >> 6, r = e & 63, pi = r >> 2, pj4 = r & 3;
    float4 v = *reinterpret_cast<const float4*>(
        x + (size_t)(b * IMG + gi * PP + pi) * IMG + gj * PP + pj4 * 4);
    *reinterpret_cast<float4*>(&patch[gj][pi * PP + pj4 * 4]) = v;
  }
  __syncthreads();
  int d = t & 127, half = t >> 7;
  float acc[7];
#pragma unroll
  for (int k = 0; k < 7; k++) acc[k] = NEGINF;
  const float4* W4 = reinterpret_cast<const float4*>(eW + (size_t)d * PD);
#pragma unroll 4
  for (int j4 = 0; j4 < PD / 4; j4++) {
    float4 w = W4[j4];
#pragma unroll
    for (int k = 0; k < 7; k++) {
      int gj = half * 7 + k;
      acc[k] = fmaxf(acc[k], patch[gj][j4 * 4 + 0] + w.x);
      acc[k] = fmaxf(acc[k], patch[gj][j4 * 4 + 1] + w.y);
      acc[k] = fmaxf(acc[k], patch[gj][j4 * 4 + 2] + w.z);
      acc[k] = fmaxf(acc[k], patch[gj][j4 * 4 + 3] + w.w);
    }
  }
#pragma unroll
  for (int k = 0; k < 7; k++) {
    int n = gi * GG + half * 7 + k;
    h[(size_t)(b * NN + n) * DD + d] = acc[k] + pos[(size_t)n * DD + d];
  }
}

// ---------------- qkv: grid (49, B), 384 threads ----------------
// W in ORIGINAL (D, D) layout; per-thread float4 rows. pnorm folded to output.
// q, k, v all stored in natural [n][d] layout.
__global__ void qkv_kernel(const float* __restrict__ h, const float* __restrict__ qW,
                           const float* __restrict__ kW, const float* __restrict__ vW,
                           float* __restrict__ q, float* __restrict__ k,
                           float* __restrict__ v) {
  int nt = blockIdx.x, b = blockIdx.y, n0 = nt * 4;
  __shared__ float xs[4][DD];
  __shared__ float mxs[4];
  int t = threadIdx.x;
  if (t < 128) {
    float4 val = reinterpret_cast<const float4*>(h + (size_t)(b * NN + n0) * DD)[t];
    *reinterpret_cast<float4*>(&xs[0][0] + t * 4) = val;
  }
  __syncthreads();
  if (t < 128) {
    int r = t >> 5, l = t & 31;
    float m = fmaxf(fmaxf(xs[r][l], xs[r][l + 32]), fmaxf(xs[r][l + 64], xs[r][l + 96]));
#pragma unroll
    for (int mask = 16; mask >= 1; mask >>= 1) m = fmaxf(m, __shfl_xor(m, mask));
    if (l == 0) mxs[r] = m;
  }
  __syncthreads();
  int m = t >> 7, i = t & 127;
  const float* W = (m == 0) ? qW : (m == 1 ? kW : vW);
  const float4* W4 = reinterpret_cast<const float4*>(W + (size_t)i * DD);
  float acc[4];
#pragma unroll
  for (int r = 0; r < 4; r++) acc[r] = NEGINF;
#pragma unroll 4
  for (int j4 = 0; j4 < DD / 4; j4++) {
    float4 w = W4[j4];
#pragma unroll
    for (int r = 0; r < 4; r++) {
      acc[r] = fmaxf(acc[r], xs[r][j4 * 4 + 0] + w.x);
      acc[r] = fmaxf(acc[r], xs[r][j4 * 4 + 1] + w.y);
      acc[r] = fmaxf(acc[r], xs[r][j4 * 4 + 2] + w.z);
      acc[r] = fmaxf(acc[r], xs[r][j4 * 4 + 3] + w.w);
    }
  }
  float* dst = (m == 0) ? q : (m == 1 ? k : v);
#pragma unroll
  for (int r = 0; r < 4; r++)
    dst[(size_t)(b * NN + n0 + r) * DD + i] = acc[r] - mxs[r];
}

// ---------------- attn: grid (49, B), 256 threads ----------------
__global__ void attn_kernel(const float* __restrict__ q, const float* __restrict__ k,
                            const float* __restrict__ v, float* __restrict__ h) {
  int it = blockIdx.x, b = blockIdx.y, i0 = it * 4;
  __shared__ float qs[4][DD];
  __shared__ float sc[4][NN];
  __shared__ float ored[8][4][DD];  // 16 KB
  __shared__ float red[2][4];
  int t = threadIdx.x;
  if (t < 128) {
    float4 val = reinterpret_cast<const float4*>(q + (size_t)(b * NN + i0) * DD)[t];
    *reinterpret_cast<float4*>(&qs[0][0] + t * 4) = val;
  }
  __syncthreads();
  // scores: thread t = key index, per-thread float4 row of k
  if (t < NN) {
    const float4* k4 = reinterpret_cast<const float4*>(k + (size_t)(b * NN + t) * DD);
    float s0 = NEGINF, s1 = NEGINF, s2 = NEGINF, s3 = NEGINF;
#pragma unroll 4
    for (int d4 = 0; d4 < DD / 4; d4++) {
      float4 kv = k4[d4];
      s0 = fmaxf(s0, qs[0][d4 * 4 + 0] + kv.x); s0 = fmaxf(s0, qs[0][d4 * 4 + 1] + kv.y);
      s0 = fmaxf(s0, qs[0][d4 * 4 + 2] + kv.z); s0 = fmaxf(s0, qs[0][d4 * 4 + 3] + kv.w);
      s1 = fmaxf(s1, qs[1][d4 * 4 + 0] + kv.x); s1 = fmaxf(s1, qs[1][d4 * 4 + 1] + kv.y);
      s1 = fmaxf(s1, qs[1][d4 * 4 + 2] + kv.z); s1 = fmaxf(s1, qs[1][d4 * 4 + 3] + kv.w);
      s2 = fmaxf(s2, qs[2][d4 * 4 + 0] + kv.x); s2 = fmaxf(s2, qs[2][d4 * 4 + 1] + kv.y);
      s2 = fmaxf(s2, qs[2][d4 * 4 + 2] + kv.z); s2 = fmaxf(s2, qs[2][d4 * 4 + 3] + kv.w);
      s3 = fmaxf(s3, qs[3][d4 * 4 + 0] + kv.x); s3 = fmaxf(s3, qs[3][d4 * 4 + 1] + kv.y);
      s3 = fmaxf(s3, qs[3][d4 * 4 + 2] + kv.z); s3 = fmaxf(s3, qs[3][d4 * 4 + 3] + kv.w);
    }
    sc[0][t] = s0; sc[1][t] = s1; sc[2][t] = s2; sc[3][t] = s3;
  }
  __syncthreads();
  // PV: threads (d4 = t&31, jg = t>>5); 25 independent float4 loads each
  {
    int d4 = t & 31, jg = t >> 5;
    float4 o0 = {NEGINF, NEGINF, NEGINF, NEGINF};
    float4 o1 = o0, o2 = o0, o3 = o0;
#pragma unroll 4
    for (int j = jg; j < NN; j += 8) {
      float4 vv = *reinterpret_cast<const float4*>(v + (size_t)(b * NN + j) * DD + d4 * 4);
      float c0 = sc[0][j], c1 = sc[1][j], c2 = sc[2][j], c3 = sc[3][j];
      o0.x = fmaxf(o0.x, c0 + vv.x); o0.y = fmaxf(o0.y, c0 + vv.y);
      o0.z = fmaxf(o0.z, c0 + vv.z); o0.w = fmaxf(o0.w, c0 + vv.w);
      o1.x = fmaxf(o1.x, c1 + vv.x); o1.y = fmaxf(o1.y, c1 + vv.y);
      o1.z = fmaxf(o1.z, c1 + vv.z); o1.w = fmaxf(o1.w, c1 + vv.w);
      o2.x = fmaxf(o2.x, c2 + vv.x); o2.y = fmaxf(o2.y, c2 + vv.y);
      o2.z = fmaxf(o2.z, c2 + vv.z); o2.w = fmaxf(o2.w, c2 + vv.w);
      o3.x = fmaxf(o3.x, c3 + vv.x); o3.y = fmaxf(o3.y, c3 + vv.y);
      o3.z = fmaxf(o3.z, c3 + vv.z); o3.w = fmaxf(o3.w, c3 + vv.w);
    }
    *reinterpret_cast<float4*>(&ored[jg][0][d4 * 4]) = o0;
    *reinterpret_cast<float4*>(&ored[jg][1][d4 * 4]) = o1;
    *reinterpret_cast<float4*>(&ored[jg][2][d4 * 4]) = o2;
    *reinterpret_cast<float4*>(&ored[jg][3][d4 * 4]) = o3;
  }
  __syncthreads();
  if (t < DD) {
    int lane = t & 63, wv = t >> 6;
    float o[4];
#pragma unroll
    for (int r = 0; r < 4; r++) {
      float m = ored[0][r][t];
#pragma unroll
      for (int g = 1; g < 8; g++) m = fmaxf(m, ored[g][r][t]);
      o[r] = m;
      float mv = m;
#pragma unroll
      for (int mask = 32; mask >= 1; mask >>= 1) mv = fmaxf(mv, __shfl_xor(mv, mask));
      if (lane == 0) red[wv][r] = mv;
    }
    __builtin_amdgcn_s_barrier();  // only waves 0-1 reach here? no: see below
    // (barrier moved outside guard — see below)
    ;
  }
  __syncthreads();
  if (t < DD) {
#pragma unroll
    for (int r = 0; r < 4; r++) {
      float m = ored[0][r][t];
#pragma unroll
      for (int g = 1; g < 8; g++) m = fmaxf(m, ored[g][r][t]);
      float omax = fmaxf(red[0][r], red[1][r]);
      size_t idx = (size_t)(b * NN + i0 + r) * DD + t;
      h[idx] = fmaxf(h[idx], m - omax);
    }
  }
}

// ---------------- ffn1: grid (49, B), 256 threads ----------------
__global__ void ffn1_kernel(const float* __restrict__ h, const float* __restrict__ f1W,
                            const float* __restrict__ tau, float* __restrict__ h1) {
  int nt = blockIdx.x, b = blockIdx.y, n0 = nt * 4;
  __shared__ float xs[4][DD];
  __shared__ float mxs[4];
  int t = threadIdx.x;
  if (t < 128) {
    float4 val = reinterpret_cast<const float4*>(h + (size_t)(b * NN + n0) * DD)[t];
    *reinterpret_cast<float4*>(&xs[0][0] + t * 4) = val;
  }
  __syncthreads();
  if (t < 128) {
    int r = t >> 5, l = t & 31;
    float m = fmaxf(fmaxf(xs[r][l], xs[r][l + 32]), fmaxf(xs[r][l + 64], xs[r][l + 96]));
#pragma unroll
    for (int mask = 16; mask >= 1; mask >>= 1) m = fmaxf(m, __shfl_xor(m, mask));
    if (l == 0) mxs[r] = m;
  }
  __syncthreads();
  float tv = tau[0];
  const float4* W4 = reinterpret_cast<const float4*>(f1W + (size_t)t * DD);
  float acc[4];
#pragma unroll
  for (int r = 0; r < 4; r++) acc[r] = NEGINF;
#pragma unroll 4
  for (int j4 = 0; j4 < DD / 4; j4++) {
    float4 w = W4[j4];
#pragma unroll
    for (int r = 0; r < 4; r++) {
      acc[r] = fmaxf(acc[r], xs[r][j4 * 4 + 0] + w.x);
      acc[r] = fmaxf(acc[r], xs[r][j4 * 4 + 1] + w.y);
      acc[r] = fmaxf(acc[r], xs[r][j4 * 4 + 2] + w.z);
      acc[r] = fmaxf(acc[r], xs[r][j4 * 4 + 3] + w.w);
    }
  }
#pragma unroll
  for (int r = 0; r < 4; r++)
    h1[(size_t)(b * NN + n0 + r) * DFFV + t] = fmaxf(acc[r] - mxs[r], tv);
}

// ---------------- ffn2: grid (49, B), 256 threads ----------------
__global__ void ffn2_kernel(const float* __restrict__ h1, const float* __restrict__ f2W,
                            float* __restrict__ h) {
  int nt = blockIdx.x, b = blockIdx.y, n0 = nt * 4;
  __shared__ float hs[4][DFFV];  // 4 KB
  __shared__ float part[2][4][DD];  // 4 KB
  __shared__ float red[2][4];
  int t = threadIdx.x;
  {
    float4 val = reinterpret_cast<const float4*>(h1 + (size_t)(b * NN + n0) * DFFV)[t];
    *reinterpret_cast<float4*>(&hs[0][0] + t * 4) = val;
  }
  __syncthreads();
  int i = t & 127, jh = t >> 7;
  const float4* W4 = reinterpret_cast<const float4*>(f2W + (size_t)i * DFFV) + jh * 32;
  float acc[4];
#pragma unroll
  for (int r = 0; r < 4; r++) acc[r] = NEGINF;
#pragma unroll 4
  for (int j4 = 0; j4 < 32; j4++) {
    float4 w = W4[j4];
    int jb = jh * 128 + j4 * 4;
#pragma unroll
    for (int r = 0; r < 4; r++) {
      acc[r] = fmaxf(acc[r], hs[r][jb + 0] + w.x);
      acc[r] = fmaxf(acc[r], hs[r][jb + 1] + w.y);
      acc[r] = fmaxf(acc[r], hs[r][jb + 2] + w.z);
      acc[r] = fmaxf(acc[r], hs[r][jb + 3] + w.w);
    }
  }
#pragma unroll
  for (int r = 0; r < 4; r++) part[jh][r][i] = acc[r];
  __syncthreads();
  if (t < DD) {
    int lane = t & 63, wv = t >> 6;
    float m[4];
#pragma unroll
    for (int r = 0; r < 4; r++) {
      m[r] = fmaxf(part[0][r][t], part[1][r][t]);
      float mv = m[r];
#pragma unroll
      for (int mask = 32; mask >= 1; mask >>= 1) mv = fmaxf(mv, __shfl_xor(mv, mask));
      if (lane == 0) red[wv][r] = mv;
    }
  }
  __syncthreads();
  if (t < DD) {
#pragma unroll
    for (int r = 0; r < 4; r++) {
      float m = fmaxf(part[0][r][t], part[1][r][t]);
      float omax = fmaxf(red[0][r], red[1][r]);
      size_t idx = (size_t)(b * NN + n0 + r) * DD + t;
      h[idx] = fmaxf(h[idx], m - omax);
    }
  }
}

// ---------------- head: grid (32, B), 256 threads ----------------
// Redundant n-parallel pooling per block, then 32 c-values via per-thread
// float4 rows of ORIGINAL head_W (C, D) layout + LDS reduce.
__global__ void head_kernel(const float* __restrict__ h, const float* __restrict__ hW,
                            const float* __restrict__ lscale, float* __restrict__ out) {
  int cc = blockIdx.x, b = blockIdx.y;
  __shared__ float plds[8][DD];     // 4 KB
  __shared__ float pooled[DD];      // 512 B
  __shared__ float gred[8][32];     // 1 KB
  int t = threadIdx.x;
  {
    int d4 = t & 31, ng = t >> 5;
    float4 pm = {NEGINF, NEGINF, NEGINF, NEGINF};
#pragma unroll 4
    for (int n = ng; n < NN; n += 8) {
      float4 hv = *reinterpret_cast<const float4*>(h + (size_t)(b * NN + n) * DD + d4 * 4);
      pm.x = fmaxf(pm.x, hv.x); pm.y = fmaxf(pm.y, hv.y);
      pm.z = fmaxf(pm.z, hv.z); pm.w = fmaxf(pm.w, hv.w);
    }
    *reinterpret_cast<float4*>(&plds[ng][d4 * 4]) = pm;
  }
  __syncthreads();
  if (t < DD) {
    float m = plds[0][t];
#pragma unroll
    for (int g = 1; g < 8; g++) m = fmaxf(m, plds[g][t]);
    pooled[t] = m;
  }
  __syncthreads();
  int cl = t & 31, ds = t >> 5;
  int c = cc * 32 + cl;
  float acc = NEGINF;
  if (c < CC) {
    const float4* W4 = reinterpret_cast<const float4*>(hW + (size_t)c * DD) + ds * 4;
#pragma unroll
    for (int kk = 0; kk < 4; kk++) {
      float4 w = W4[kk];
      int db = ds * 16 + kk * 4;
      acc = fmaxf(acc, pooled[db + 0] + w.x);
      acc = fmaxf(acc, pooled[db + 1] + w.y);
      acc = fmaxf(acc, pooled[db + 2] + w.z);
      acc = fmaxf(acc, pooled[db + 3] + w.w);
    }
  }
  gred[ds][cl] = acc;
  __syncthreads();
  if (t < 32) {
    int c2 = cc * 32 + t;
    if (c2 < CC) {
      float m = gred[0][t];
#pragma unroll
      for (int g = 1; g < 8; g++) m = fmaxf(m, gred[g][t]);
      out[(size_t)b * CC + c2] = m * lscale[0];
    }
  }
}

extern "C" void kernel_launch(void* const* d_in, const int* in_sizes, int n_in,
                              void* d_out, int out_size, void* d_ws, size_t ws_size,
                              hipStream_t stream) {
  const float* x = (const float*)d_in[0];
  const float* embed_W = (const float*)d_in[1];
  const float* pos = (const float*)d_in[2];
  const float* qW[2] = {(const float*)d_in[3], (const float*)d_in[9]};
  const float* kW[2] = {(const float*)d_in[4], (const float*)d_in[10]};
  const float* vW[2] = {(const float*)d_in[5], (const float*)d_in[11]};
  const float* f1W[2] = {(const float*)d_in[6], (const float*)d_in[12]};
  const float* f2W[2] = {(const float*)d_in[7], (const float*)d_in[13]};
  const float* tau[2] = {(const float*)d_in[8], (const float*)d_in[14]};
  const float* headW = (const float*)d_in[15];
  const float* lscale = (const float*)d_in[16];
  float* out = (float*)d_out;

  float* ws = (float*)d_ws;
  size_t o = 0;
  float* h = ws + o; o += (size_t)BDIM * NN * DD;
  float* qb = ws + o; o += (size_t)BDIM * NN * DD;
  float* kb = ws + o; o += (size_t)BDIM * NN * DD;
  float* vb = ws + o; o += (size_t)BDIM * NN * DD;
  float* h1 = ws + o; o += (size_t)BDIM * NN * DFFV;

  embed_kernel<<<BDIM * GG, 256, 0, stream>>>(x, embed_W, pos, h);
  for (int l = 0; l < 2; l++) {
    qkv_kernel<<<dim3(49, BDIM), 384, 0, stream>>>(h, qW[l], kW[l], vW[l], qb, kb, vb);
    attn_kernel<<<dim3(49, BDIM), 256, 0, stream>>>(qb, kb, vb, h);
    ffn1_kernel<<<dim3(49, BDIM), 256, 0, stream>>>(h, f1W[l], tau[l], h1);
    ffn2_kernel<<<dim3(49, BDIM), 256, 0, stream>>>(h1, f2W[l], h);
  }
  head_kernel<<<dim3(32, BDIM), 256, 0, stream>>>(h, headW, lscale, out);
}